// Round 1
// baseline (791.257 us; speedup 1.0000x reference)
//
#include <hip/hip_runtime.h>
#include <hip/hip_bf16.h>

typedef unsigned long long u64;

#define EPSV 1e-5

__device__ __forceinline__ int imax(int a, int b) { return a > b ? a : b; }

// ---------------- conv0: real input [256,3,32,32], binarized weights, 3x3 pad1, + maxpool2 ----------------
// out: preBN [256,64,16,16] fp32
__global__ __launch_bounds__(256) void conv0_kernel(const float* __restrict__ x,
                                                    const float* __restrict__ wgt,
                                                    const float* __restrict__ bias,
                                                    float* __restrict__ out) {
    const int co = blockIdx.y;
    int idx = blockIdx.x * 256 + threadIdx.x;  // n*256 + yp*16 + xp
    if (idx >= 256 * 16 * 16) return;
    const int xp = idx & 15;
    const int yp = (idx >> 4) & 15;
    const int n = idx >> 8;

    float ws[3][3][3];
#pragma unroll
    for (int ci = 0; ci < 3; ++ci)
#pragma unroll
        for (int ky = 0; ky < 3; ++ky)
#pragma unroll
            for (int kx = 0; kx < 3; ++kx)
                ws[ci][ky][kx] = (wgt[((co * 3 + ci) * 3 + ky) * 3 + kx] >= 0.f) ? 1.f : -1.f;

    float acc[2][2] = {{0.f, 0.f}, {0.f, 0.f}};
    const float* xb = x + (size_t)n * 3 * 32 * 32;
    const int y0 = 2 * yp - 1, x0 = 2 * xp - 1;
#pragma unroll
    for (int ci = 0; ci < 3; ++ci) {
        float win[4][4];
#pragma unroll
        for (int r = 0; r < 4; ++r) {
            int yy = y0 + r;
#pragma unroll
            for (int c = 0; c < 4; ++c) {
                int xx = x0 + c;
                bool v = ((unsigned)yy < 32u) && ((unsigned)xx < 32u);
                win[r][c] = v ? xb[(ci * 32 + yy) * 32 + xx] : 0.f;
            }
        }
#pragma unroll
        for (int py = 0; py < 2; ++py)
#pragma unroll
            for (int px = 0; px < 2; ++px)
#pragma unroll
                for (int ky = 0; ky < 3; ++ky)
#pragma unroll
                    for (int kx = 0; kx < 3; ++kx)
                        acc[py][px] += win[py + ky][px + kx] * ws[ci][ky][kx];
    }
    float b = bias[co];
    float val = fmaxf(fmaxf(acc[0][0], acc[0][1]), fmaxf(acc[1][0], acc[1][1])) + b;
    out[((size_t)n * 64 + co) * 256 + yp * 16 + xp] = val;
}

// ---------------- binary conv (xor/popcount), optional fused maxpool2 ----------------
// in: packed [256, CW, HIN, HIN] u64 (bit j of word w = channel 64w+j, 1 means +1)
// wpk: [Co, 3, 3, CW]
// out: preBN fp32 [256, Co, HP, HP]
template <int CW, int HIN, bool POOL>
__global__ __launch_bounds__(256) void bconv_kernel(const u64* __restrict__ in,
                                                    const u64* __restrict__ wpk,
                                                    const float* __restrict__ bias,
                                                    float* __restrict__ out, int Co) {
    constexpr int HP = POOL ? HIN / 2 : HIN;
    constexpr int WS = POOL ? 4 : 3;
    constexpr int NACC = POOL ? 4 : 1;
    const int co = blockIdx.y;
    int idx = blockIdx.x * 256 + threadIdx.x;
    constexpr int NPIX = 256 * HP * HP;
    if (idx >= NPIX) return;
    const int xp = idx % HP;
    int t = idx / HP;
    const int yp = t % HP;
    const int n = t / HP;
    const int y0 = (POOL ? 2 * yp : yp) - 1;
    const int x0 = (POOL ? 2 * xp : xp) - 1;

    bool vld[WS][WS];
#pragma unroll
    for (int r = 0; r < WS; ++r) {
        int yy = y0 + r;
        bool vy = (unsigned)yy < (unsigned)HIN;
#pragma unroll
        for (int c = 0; c < WS; ++c) {
            int xx = x0 + c;
            vld[r][c] = vy && ((unsigned)xx < (unsigned)HIN);
        }
    }

    int acc[NACC];
#pragma unroll
    for (int i = 0; i < NACC; ++i) acc[i] = 0;

    const u64* wrow = wpk + (size_t)co * 9 * CW;
    const u64* inb = in + (size_t)n * CW * HIN * HIN;

#pragma unroll 1
    for (int w = 0; w < CW; ++w) {
        u64 win[WS][WS];
#pragma unroll
        for (int r = 0; r < WS; ++r)
#pragma unroll
            for (int c = 0; c < WS; ++c)
                win[r][c] = vld[r][c] ? inb[((size_t)w * HIN + (y0 + r)) * HIN + (x0 + c)] : 0ULL;
        u64 wb[9];
#pragma unroll
        for (int k = 0; k < 9; ++k) wb[k] = wrow[k * CW + w];
        if constexpr (POOL) {
#pragma unroll
            for (int py = 0; py < 2; ++py)
#pragma unroll
                for (int px = 0; px < 2; ++px)
#pragma unroll
                    for (int ky = 0; ky < 3; ++ky)
#pragma unroll
                        for (int kx = 0; kx < 3; ++kx)
                            if (vld[py + ky][px + kx])
                                acc[py * 2 + px] +=
                                    64 - 2 * (int)__popcll(win[py + ky][px + kx] ^ wb[ky * 3 + kx]);
        } else {
#pragma unroll
            for (int ky = 0; ky < 3; ++ky)
#pragma unroll
                for (int kx = 0; kx < 3; ++kx)
                    if (vld[ky][kx]) acc[0] += 64 - 2 * (int)__popcll(win[ky][kx] ^ wb[ky * 3 + kx]);
        }
    }
    float b = bias[co];
    float val;
    if constexpr (POOL) {
        val = (float)imax(imax(acc[0], acc[1]), imax(acc[2], acc[3])) + b;
    } else {
        val = (float)acc[0] + b;
    }
    out[((size_t)n * Co + co) * (HP * HP) + yp * HP + xp] = val;
}

// ---------------- per-channel batch stats (mean, invstd), deterministic double reduction ----------------
__global__ __launch_bounds__(256) void stats_kernel(const float* __restrict__ pre,
                                                    float2* __restrict__ stats, int Co, int HW) {
    int co = blockIdx.x;
    double s1 = 0.0, s2 = 0.0;
    int count = 256 * HW;
    for (int i = threadIdx.x; i < count; i += 256) {
        int n = i / HW, r = i % HW;
        float v = pre[((size_t)n * Co + co) * HW + r];
        s1 += (double)v;
        s2 += (double)v * (double)v;
    }
    __shared__ double sh1[256], sh2[256];
    sh1[threadIdx.x] = s1;
    sh2[threadIdx.x] = s2;
    __syncthreads();
    for (int s = 128; s > 0; s >>= 1) {
        if (threadIdx.x < s) {
            sh1[threadIdx.x] += sh1[threadIdx.x + s];
            sh2[threadIdx.x] += sh2[threadIdx.x + s];
        }
        __syncthreads();
    }
    if (threadIdx.x == 0) {
        double m = sh1[0] / count;
        double var = sh2[0] / count - m * m;
        stats[co] = make_float2((float)m, (float)(1.0 / sqrt(var + EPSV)));
    }
}

// ---------------- BN apply + (hardtanh) + sign + bit-pack for next layer ----------------
// pre [256, Co, HW] -> packed [256, Co/64, HW]
__global__ __launch_bounds__(256) void bnpack_kernel(const float* __restrict__ pre,
                                                     const float2* __restrict__ stats,
                                                     const float* __restrict__ g,
                                                     const float* __restrict__ bta,
                                                     u64* __restrict__ outp, int Co, int HW) {
    int CW = Co >> 6;
    int idx = blockIdx.x * 256 + threadIdx.x;
    int total = 256 * CW * HW;
    if (idx >= total) return;
    int r = idx % HW;
    int t = idx / HW;
    int w = t % CW;
    int n = t / CW;
    u64 bits = 0;
    for (int j = 0; j < 64; ++j) {
        int c = (w << 6) + j;
        float v = pre[((size_t)n * Co + c) * HW + r];
        float2 st = stats[c];
        float z = g[c] * (v - st.x) * st.y + bta[c];
        bits |= (u64)(z >= 0.0f) << j;
    }
    outp[idx] = bits;
}

// ---------------- weight packing ----------------
__global__ void wpack_conv(const float* __restrict__ w, u64* __restrict__ wp, int Co, int Ci) {
    int CW = Ci >> 6;
    int idx = blockIdx.x * 256 + threadIdx.x;
    int total = Co * 9 * CW;
    if (idx >= total) return;
    int ww = idx % CW;
    int t = idx / CW;
    int k = t % 9;
    int co = t / 9;
    int ky = k / 3, kx = k % 3;
    u64 bits = 0;
    for (int j = 0; j < 64; ++j) {
        float v = w[(((size_t)co * Ci + (ww << 6) + j) * 3 + ky) * 3 + kx];
        bits |= (u64)(v >= 0.f) << j;
    }
    wp[idx] = bits;
}

__global__ void wpack_lin(const float* __restrict__ w, u64* __restrict__ wp, int O) {
    int idx = blockIdx.x * 256 + threadIdx.x;
    int total = O * 8;
    if (idx >= total) return;
    int ww = idx & 7;
    int o = idx >> 3;
    u64 bits = 0;
    const float* row = w + (size_t)o * 512 + (ww << 6);
    for (int j = 0; j < 64; ++j) bits |= (u64)(row[j] >= 0.f) << j;
    wp[idx] = bits;
}

// ---------------- binarized linear + BN1 (+ hardtanh) ----------------
// hp [256,8] packed rows, wp [O,8], writes z [256,O]
__global__ __launch_bounds__(256) void lin_kernel(const u64* __restrict__ hp,
                                                  const u64* __restrict__ wp,
                                                  const float* __restrict__ lb,
                                                  const float* __restrict__ g,
                                                  const float* __restrict__ bta,
                                                  float* __restrict__ z, int O, int applyHt) {
    int o = blockIdx.x;
    int n = threadIdx.x;  // N == 256 == blockDim
    const u64* hr = hp + n * 8;
    const u64* wr = wp + o * 8;
    int s = 0;
#pragma unroll
    for (int w = 0; w < 8; ++w) s += (int)__popcll(hr[w] ^ wr[w]);
    float val = (float)(512 - 2 * s) + lb[o];
    __shared__ double sh1[256], sh2[256];
    sh1[n] = (double)val;
    sh2[n] = (double)val * (double)val;
    __syncthreads();
    for (int st = 128; st > 0; st >>= 1) {
        if (n < st) {
            sh1[n] += sh1[n + st];
            sh2[n] += sh2[n + st];
        }
        __syncthreads();
    }
    __shared__ float sm, siv;
    if (n == 0) {
        double m = sh1[0] / 256.0;
        double var = sh2[0] / 256.0 - m * m;
        sm = (float)m;
        siv = (float)(1.0 / sqrt(var + EPSV));
    }
    __syncthreads();
    float zz = g[o] * (val - sm) * siv + bta[o];
    if (applyHt) zz = fminf(1.f, fmaxf(-1.f, zz));
    z[(size_t)n * O + o] = zz;
}

// pack post-ht FC activations [256,512] -> [256,8]
__global__ void pack_rows(const float* __restrict__ z, u64* __restrict__ hp) {
    int idx = blockIdx.x * 256 + threadIdx.x;  // 2048 total
    if (idx >= 2048) return;
    int ww = idx & 7;
    int n = idx >> 3;
    u64 bits = 0;
    const float* row = z + (size_t)n * 512 + (ww << 6);
    for (int j = 0; j < 64; ++j) bits |= (u64)(row[j] >= 0.f) << j;
    hp[idx] = bits;
}

// ---------------- log_softmax over 10 classes ----------------
__global__ void lsm_kernel(const float* __restrict__ z, float* __restrict__ out) {
    int n = blockIdx.x * 64 + threadIdx.x;
    if (n >= 256) return;
    float v[10];
    float m = -1e30f;
#pragma unroll
    for (int i = 0; i < 10; ++i) {
        v[i] = z[n * 10 + i];
        m = fmaxf(m, v[i]);
    }
    float s = 0.f;
#pragma unroll
    for (int i = 0; i < 10; ++i) s += expf(v[i] - m);
    float ls = logf(s);
#pragma unroll
    for (int i = 0; i < 10; ++i) out[n * 10 + i] = v[i] - m - ls;
}

extern "C" void kernel_launch(void* const* d_in, const int* in_sizes, int n_in, void* d_out,
                              int out_size, void* d_ws, size_t ws_size, hipStream_t stream) {
    (void)in_sizes; (void)n_in; (void)out_size; (void)ws_size;
    const float* x = (const float*)d_in[0];
    const float *cw[8], *cb[8], *cg[8], *ct[8];
    for (int i = 0; i < 8; ++i) {
        cw[i] = (const float*)d_in[1 + 4 * i];
        cb[i] = (const float*)d_in[2 + 4 * i];
        cg[i] = (const float*)d_in[3 + 4 * i];
        ct[i] = (const float*)d_in[4 + 4 * i];
    }
    const float *lw[3], *lb[3], *lg[3], *lt[3];
    for (int i = 0; i < 3; ++i) {
        lw[i] = (const float*)d_in[33 + 4 * i];
        lb[i] = (const float*)d_in[34 + 4 * i];
        lg[i] = (const float*)d_in[35 + 4 * i];
        lt[i] = (const float*)d_in[36 + 4 * i];
    }

    static const int CIs[8] = {3, 64, 128, 256, 256, 512, 512, 512};
    static const int COs[8] = {64, 128, 256, 256, 512, 512, 512, 512};
    static const int HPs[8] = {16, 8, 8, 4, 4, 2, 2, 1};  // output spatial (post-pool where applicable)

    char* ws = (char*)d_ws;
    size_t off = 0;
    auto alloc = [&](size_t bytes) -> void* {
        void* p = ws + off;
        off += (bytes + 255) & ~(size_t)255;
        return p;
    };

    u64* wpk[8];
    for (int i = 1; i < 8; ++i) wpk[i] = (u64*)alloc((size_t)COs[i] * 9 * (CIs[i] / 64) * 8);
    u64* wpl[3];
    int LO[3] = {512, 512, 10};
    for (int i = 0; i < 3; ++i) wpl[i] = (u64*)alloc((size_t)LO[i] * 8 * 8);
    u64* act[8];
    for (int i = 0; i < 8; ++i) act[i] = (u64*)alloc((size_t)256 * (COs[i] / 64) * HPs[i] * HPs[i] * 8);
    u64* fcs0 = (u64*)alloc(2048 * 8);
    u64* fcs1 = (u64*)alloc(2048 * 8);
    float* preA = (float*)alloc((size_t)4194304 * 4);  // even conv layers (max 256*256*8*8)
    float* preB = (float*)alloc((size_t)2097152 * 4);  // odd conv layers (max 256*128*8*8)
    float2* stats = (float2*)alloc(512 * 8);
    float* z0 = (float*)alloc((size_t)256 * 512 * 4);
    float* z1 = (float*)alloc((size_t)256 * 512 * 4);
    float* z2 = (float*)alloc((size_t)256 * 10 * 4);

    // ---- pack weights ----
    for (int i = 1; i < 8; ++i) {
        int total = COs[i] * 9 * (CIs[i] / 64);
        wpack_conv<<<(total + 255) / 256, 256, 0, stream>>>(cw[i], wpk[i], COs[i], CIs[i]);
    }
    for (int i = 0; i < 3; ++i) {
        int total = LO[i] * 8;
        wpack_lin<<<(total + 255) / 256, 256, 0, stream>>>(lw[i], wpl[i], LO[i]);
    }

    // ---- conv0 (real input) ----
    conv0_kernel<<<dim3(256, 64), 256, 0, stream>>>(x, cw[0], cb[0], preA);
    stats_kernel<<<64, 256, 0, stream>>>(preA, stats, 64, 256);
    bnpack_kernel<<<(256 * 1 * 256 + 255) / 256, 256, 0, stream>>>(preA, stats, cg[0], ct[0],
                                                                   act[0], 64, 256);
    // ---- conv1: 64ch 16x16 -> 128ch, pool -> 8x8 ----
    bconv_kernel<1, 16, true><<<dim3(64, 128), 256, 0, stream>>>(act[0], wpk[1], cb[1], preB, 128);
    stats_kernel<<<128, 256, 0, stream>>>(preB, stats, 128, 64);
    bnpack_kernel<<<(256 * 2 * 64 + 255) / 256, 256, 0, stream>>>(preB, stats, cg[1], ct[1], act[1],
                                                                  128, 64);
    // ---- conv2: 128ch 8x8 -> 256ch (no pool) ----
    bconv_kernel<2, 8, false><<<dim3(64, 256), 256, 0, stream>>>(act[1], wpk[2], cb[2], preA, 256);
    stats_kernel<<<256, 256, 0, stream>>>(preA, stats, 256, 64);
    bnpack_kernel<<<(256 * 4 * 64 + 255) / 256, 256, 0, stream>>>(preA, stats, cg[2], ct[2], act[2],
                                                                  256, 64);
    // ---- conv3: 256ch 8x8 -> 256ch, pool -> 4x4 ----
    bconv_kernel<4, 8, true><<<dim3(16, 256), 256, 0, stream>>>(act[2], wpk[3], cb[3], preB, 256);
    stats_kernel<<<256, 256, 0, stream>>>(preB, stats, 256, 16);
    bnpack_kernel<<<(256 * 4 * 16 + 255) / 256, 256, 0, stream>>>(preB, stats, cg[3], ct[3], act[3],
                                                                  256, 16);
    // ---- conv4: 256ch 4x4 -> 512ch (no pool) ----
    bconv_kernel<4, 4, false><<<dim3(16, 512), 256, 0, stream>>>(act[3], wpk[4], cb[4], preA, 512);
    stats_kernel<<<512, 256, 0, stream>>>(preA, stats, 512, 16);
    bnpack_kernel<<<(256 * 8 * 16 + 255) / 256, 256, 0, stream>>>(preA, stats, cg[4], ct[4], act[4],
                                                                  512, 16);
    // ---- conv5: 512ch 4x4 -> 512ch, pool -> 2x2 ----
    bconv_kernel<8, 4, true><<<dim3(4, 512), 256, 0, stream>>>(act[4], wpk[5], cb[5], preB, 512);
    stats_kernel<<<512, 256, 0, stream>>>(preB, stats, 512, 4);
    bnpack_kernel<<<(256 * 8 * 4 + 255) / 256, 256, 0, stream>>>(preB, stats, cg[5], ct[5], act[5],
                                                                 512, 4);
    // ---- conv6: 512ch 2x2 -> 512ch (no pool) ----
    bconv_kernel<8, 2, false><<<dim3(4, 512), 256, 0, stream>>>(act[5], wpk[6], cb[6], preA, 512);
    stats_kernel<<<512, 256, 0, stream>>>(preA, stats, 512, 4);
    bnpack_kernel<<<(256 * 8 * 4 + 255) / 256, 256, 0, stream>>>(preA, stats, cg[6], ct[6], act[6],
                                                                 512, 4);
    // ---- conv7: 512ch 2x2 -> 512ch, pool -> 1x1 ----
    bconv_kernel<8, 2, true><<<dim3(1, 512), 256, 0, stream>>>(act[6], wpk[7], cb[7], preB, 512);
    stats_kernel<<<512, 256, 0, stream>>>(preB, stats, 512, 1);
    bnpack_kernel<<<(256 * 8 * 1 + 255) / 256, 256, 0, stream>>>(preB, stats, cg[7], ct[7], act[7],
                                                                 512, 1);

    // ---- FC ----
    lin_kernel<<<512, 256, 0, stream>>>(act[7], wpl[0], lb[0], lg[0], lt[0], z0, 512, 1);
    pack_rows<<<8, 256, 0, stream>>>(z0, fcs0);
    lin_kernel<<<512, 256, 0, stream>>>(fcs0, wpl[1], lb[1], lg[1], lt[1], z1, 512, 1);
    pack_rows<<<8, 256, 0, stream>>>(z1, fcs1);
    lin_kernel<<<10, 256, 0, stream>>>(fcs1, wpl[2], lb[2], lg[2], lt[2], z2, 10, 0);
    lsm_kernel<<<4, 64, 0, stream>>>(z2, (float*)d_out);
}

// Round 2
// 752.973 us; speedup vs baseline: 1.0508x; 1.0508x over previous
//
#include <hip/hip_runtime.h>
#include <hip/hip_bf16.h>

typedef unsigned long long u64;

#define EPSV 1e-5

__device__ __forceinline__ int imax(int a, int b) { return a > b ? a : b; }

// ---------------- zero the stats accumulators (8 layers x 512 ch x 2 words) ----------------
__global__ void zero_acc(u64* __restrict__ p, int n) {
    int i = blockIdx.x * 256 + threadIdx.x;
    if (i < n) p[i] = 0ULL;
}

// ---------------- conv0: real input [256,3,32,32], binarized weights, 3x3 pad1, + maxpool2 ----------------
// out: preBN [256,64,16,16] fp32; fused stats accumulation (double atomics)
__global__ __launch_bounds__(256) void conv0_kernel(const float* __restrict__ x,
                                                    const float* __restrict__ wgt,
                                                    const float* __restrict__ bias,
                                                    float* __restrict__ out,
                                                    double* __restrict__ dacc) {
    const int co = blockIdx.y;
    int idx = blockIdx.x * 256 + threadIdx.x;  // n*256 + yp*16 + xp  (exact grid, no strays)
    const int xp = idx & 15;
    const int yp = (idx >> 4) & 15;
    const int n = idx >> 8;

    float ws[3][3][3];
#pragma unroll
    for (int ci = 0; ci < 3; ++ci)
#pragma unroll
        for (int ky = 0; ky < 3; ++ky)
#pragma unroll
            for (int kx = 0; kx < 3; ++kx)
                ws[ci][ky][kx] = (wgt[((co * 3 + ci) * 3 + ky) * 3 + kx] >= 0.f) ? 1.f : -1.f;

    float acc[2][2] = {{0.f, 0.f}, {0.f, 0.f}};
    const float* xb = x + (size_t)n * 3 * 32 * 32;
    const int y0 = 2 * yp - 1, x0 = 2 * xp - 1;
#pragma unroll
    for (int ci = 0; ci < 3; ++ci) {
        float win[4][4];
#pragma unroll
        for (int r = 0; r < 4; ++r) {
            int yy = y0 + r;
#pragma unroll
            for (int c = 0; c < 4; ++c) {
                int xx = x0 + c;
                bool v = ((unsigned)yy < 32u) && ((unsigned)xx < 32u);
                win[r][c] = v ? xb[(ci * 32 + yy) * 32 + xx] : 0.f;
            }
        }
#pragma unroll
        for (int py = 0; py < 2; ++py)
#pragma unroll
            for (int px = 0; px < 2; ++px)
#pragma unroll
                for (int ky = 0; ky < 3; ++ky)
#pragma unroll
                    for (int kx = 0; kx < 3; ++kx)
                        acc[py][px] += win[py + ky][px + kx] * ws[ci][ky][kx];
    }
    // maxpool (pre-bias value used for stats; bias is per-channel shift handled in finalize)
    float mval = fmaxf(fmaxf(acc[0][0], acc[0][1]), fmaxf(acc[1][0], acc[1][1]));
    out[((size_t)n * 64 + co) * 256 + yp * 16 + xp] = mval + bias[co];

    // fused stats: block tree-reduce double sums, one atomic pair per block
    __shared__ double sh1[256], sh2[256];
    sh1[threadIdx.x] = (double)mval;
    sh2[threadIdx.x] = (double)mval * (double)mval;
    __syncthreads();
    for (int s = 128; s > 0; s >>= 1) {
        if (threadIdx.x < s) {
            sh1[threadIdx.x] += sh1[threadIdx.x + s];
            sh2[threadIdx.x] += sh2[threadIdx.x + s];
        }
        __syncthreads();
    }
    if (threadIdx.x == 0) {
        atomicAdd(&dacc[2 * co], sh1[0]);
        atomicAdd(&dacc[2 * co + 1], sh2[0]);
    }
}

// ---------------- binary conv (xor/popcount), optional fused maxpool2, fused int64 stats ----------------
// in: packed [256, CW, HIN, HIN] u64 (bit j of word w = channel 64w+j, 1 means +1)
// wpk: [Co, 3, 3, CW] ; out: preBN fp32 [256, Co, HP, HP] (bias included)
// iacc: per-channel {Σacc, Σacc²} int64 (bias excluded — exact)
template <int CW, int HIN, bool POOL>
__global__ __launch_bounds__(256) void bconv_kernel(const u64* __restrict__ in,
                                                    const u64* __restrict__ wpk,
                                                    const float* __restrict__ bias,
                                                    float* __restrict__ out, int Co,
                                                    u64* __restrict__ iacc) {
    constexpr int HP = POOL ? HIN / 2 : HIN;
    constexpr int WS = POOL ? 4 : 3;
    constexpr int NACC = POOL ? 4 : 1;
    const int co = blockIdx.y;
    int idx = blockIdx.x * 256 + threadIdx.x;  // exact grid: 256*HP*HP threads
    const int xp = idx % HP;
    int t = idx / HP;
    const int yp = t % HP;
    const int n = t / HP;
    const int y0 = (POOL ? 2 * yp : yp) - 1;
    const int x0 = (POOL ? 2 * xp : xp) - 1;

    bool vld[WS][WS];
#pragma unroll
    for (int r = 0; r < WS; ++r) {
        int yy = y0 + r;
        bool vy = (unsigned)yy < (unsigned)HIN;
#pragma unroll
        for (int c = 0; c < WS; ++c) {
            int xx = x0 + c;
            vld[r][c] = vy && ((unsigned)xx < (unsigned)HIN);
        }
    }

    int acc[NACC];
#pragma unroll
    for (int i = 0; i < NACC; ++i) acc[i] = 0;

    const u64* wrow = wpk + (size_t)co * 9 * CW;
    const u64* inb = in + (size_t)n * CW * HIN * HIN;

#pragma unroll 1
    for (int w = 0; w < CW; ++w) {
        u64 win[WS][WS];
#pragma unroll
        for (int r = 0; r < WS; ++r)
#pragma unroll
            for (int c = 0; c < WS; ++c)
                win[r][c] = vld[r][c] ? inb[((size_t)w * HIN + (y0 + r)) * HIN + (x0 + c)] : 0ULL;
        u64 wb[9];
#pragma unroll
        for (int k = 0; k < 9; ++k) wb[k] = wrow[k * CW + w];
        if constexpr (POOL) {
#pragma unroll
            for (int py = 0; py < 2; ++py)
#pragma unroll
                for (int px = 0; px < 2; ++px)
#pragma unroll
                    for (int ky = 0; ky < 3; ++ky)
#pragma unroll
                        for (int kx = 0; kx < 3; ++kx)
                            if (vld[py + ky][px + kx])
                                acc[py * 2 + px] +=
                                    64 - 2 * (int)__popcll(win[py + ky][px + kx] ^ wb[ky * 3 + kx]);
        } else {
#pragma unroll
            for (int ky = 0; ky < 3; ++ky)
#pragma unroll
                for (int kx = 0; kx < 3; ++kx)
                    if (vld[ky][kx]) acc[0] += 64 - 2 * (int)__popcll(win[ky][kx] ^ wb[ky * 3 + kx]);
        }
    }
    int ival;
    if constexpr (POOL) {
        ival = imax(imax(acc[0], acc[1]), imax(acc[2], acc[3]));
    } else {
        ival = acc[0];
    }
    out[((size_t)n * Co + co) * (HP * HP) + yp * HP + xp] = (float)ival + bias[co];

    // fused exact int64 stats
    __shared__ long long sh1[256], sh2[256];
    sh1[threadIdx.x] = (long long)ival;
    sh2[threadIdx.x] = (long long)ival * (long long)ival;
    __syncthreads();
    for (int s = 128; s > 0; s >>= 1) {
        if (threadIdx.x < s) {
            sh1[threadIdx.x] += sh1[threadIdx.x + s];
            sh2[threadIdx.x] += sh2[threadIdx.x + s];
        }
        __syncthreads();
    }
    if (threadIdx.x == 0) {
        atomicAdd(&iacc[2 * co], (u64)sh1[0]);
        atomicAdd(&iacc[2 * co + 1], (u64)sh2[0]);
    }
}

// ---------------- finalize: int64 sums -> (mean, invstd) ----------------
__global__ void finalize_int(const u64* __restrict__ iacc, const float* __restrict__ bias,
                             float2* __restrict__ stats, int Co, int count) {
    int i = blockIdx.x * 256 + threadIdx.x;
    if (i >= Co) return;
    long long S1 = (long long)iacc[2 * i];
    long long S2 = (long long)iacc[2 * i + 1];
    double m = (double)S1 / count;
    double var = (double)S2 / count - m * m;
    stats[i] = make_float2((float)(m + (double)bias[i]), (float)(1.0 / sqrt(var + EPSV)));
}

__global__ void finalize_dbl(const double* __restrict__ dacc, const float* __restrict__ bias,
                             float2* __restrict__ stats, int Co, int count) {
    int i = blockIdx.x * 256 + threadIdx.x;
    if (i >= Co) return;
    double S1 = dacc[2 * i];
    double S2 = dacc[2 * i + 1];
    double m = S1 / count;
    double var = S2 / count - m * m;
    stats[i] = make_float2((float)(m + (double)bias[i]), (float)(1.0 / sqrt(var + EPSV)));
}

// ---------------- BN apply + sign + bit-pack for next layer ----------------
// pre [256, Co, HW] -> packed [256, Co/64, HW]
__global__ __launch_bounds__(256) void bnpack_kernel(const float* __restrict__ pre,
                                                     const float2* __restrict__ stats,
                                                     const float* __restrict__ g,
                                                     const float* __restrict__ bta,
                                                     u64* __restrict__ outp, int Co, int HW) {
    int CW = Co >> 6;
    int idx = blockIdx.x * 256 + threadIdx.x;
    int total = 256 * CW * HW;
    if (idx >= total) return;
    int r = idx % HW;
    int t = idx / HW;
    int w = t % CW;
    int n = t / CW;
    u64 bits = 0;
    for (int j = 0; j < 64; ++j) {
        int c = (w << 6) + j;
        float v = pre[((size_t)n * Co + c) * HW + r];
        float2 st = stats[c];
        float z = g[c] * (v - st.x) * st.y + bta[c];
        bits |= (u64)(z >= 0.0f) << j;
    }
    outp[idx] = bits;
}

// ---------------- weight packing ----------------
__global__ void wpack_conv(const float* __restrict__ w, u64* __restrict__ wp, int Co, int Ci) {
    int CW = Ci >> 6;
    int idx = blockIdx.x * 256 + threadIdx.x;
    int total = Co * 9 * CW;
    if (idx >= total) return;
    int ww = idx % CW;
    int t = idx / CW;
    int k = t % 9;
    int co = t / 9;
    int ky = k / 3, kx = k % 3;
    u64 bits = 0;
    for (int j = 0; j < 64; ++j) {
        float v = w[(((size_t)co * Ci + (ww << 6) + j) * 3 + ky) * 3 + kx];
        bits |= (u64)(v >= 0.f) << j;
    }
    wp[idx] = bits;
}

__global__ void wpack_lin(const float* __restrict__ w, u64* __restrict__ wp, int O) {
    int idx = blockIdx.x * 256 + threadIdx.x;
    int total = O * 8;
    if (idx >= total) return;
    int ww = idx & 7;
    int o = idx >> 3;
    u64 bits = 0;
    const float* row = w + (size_t)o * 512 + (ww << 6);
    for (int j = 0; j < 64; ++j) bits |= (u64)(row[j] >= 0.f) << j;
    wp[idx] = bits;
}

// ---------------- binarized linear + BN1 (+ hardtanh) ----------------
__global__ __launch_bounds__(256) void lin_kernel(const u64* __restrict__ hp,
                                                  const u64* __restrict__ wp,
                                                  const float* __restrict__ lb,
                                                  const float* __restrict__ g,
                                                  const float* __restrict__ bta,
                                                  float* __restrict__ z, int O, int applyHt) {
    int o = blockIdx.x;
    int n = threadIdx.x;  // N == 256 == blockDim
    const u64* hr = hp + n * 8;
    const u64* wr = wp + o * 8;
    int s = 0;
#pragma unroll
    for (int w = 0; w < 8; ++w) s += (int)__popcll(hr[w] ^ wr[w]);
    float val = (float)(512 - 2 * s) + lb[o];
    __shared__ double sh1[256], sh2[256];
    sh1[n] = (double)val;
    sh2[n] = (double)val * (double)val;
    __syncthreads();
    for (int st = 128; st > 0; st >>= 1) {
        if (n < st) {
            sh1[n] += sh1[n + st];
            sh2[n] += sh2[n + st];
        }
        __syncthreads();
    }
    __shared__ float sm, siv;
    if (n == 0) {
        double m = sh1[0] / 256.0;
        double var = sh2[0] / 256.0 - m * m;
        sm = (float)m;
        siv = (float)(1.0 / sqrt(var + EPSV));
    }
    __syncthreads();
    float zz = g[o] * (val - sm) * siv + bta[o];
    if (applyHt) zz = fminf(1.f, fmaxf(-1.f, zz));
    z[(size_t)n * O + o] = zz;
}

// pack post-ht FC activations [256,512] -> [256,8]
__global__ void pack_rows(const float* __restrict__ z, u64* __restrict__ hp) {
    int idx = blockIdx.x * 256 + threadIdx.x;  // 2048 total
    if (idx >= 2048) return;
    int ww = idx & 7;
    int n = idx >> 3;
    u64 bits = 0;
    const float* row = z + (size_t)n * 512 + (ww << 6);
    for (int j = 0; j < 64; ++j) bits |= (u64)(row[j] >= 0.f) << j;
    hp[idx] = bits;
}

// ---------------- log_softmax over 10 classes ----------------
__global__ void lsm_kernel(const float* __restrict__ z, float* __restrict__ out) {
    int n = blockIdx.x * 64 + threadIdx.x;
    if (n >= 256) return;
    float v[10];
    float m = -1e30f;
#pragma unroll
    for (int i = 0; i < 10; ++i) {
        v[i] = z[n * 10 + i];
        m = fmaxf(m, v[i]);
    }
    float s = 0.f;
#pragma unroll
    for (int i = 0; i < 10; ++i) s += expf(v[i] - m);
    float ls = logf(s);
#pragma unroll
    for (int i = 0; i < 10; ++i) out[n * 10 + i] = v[i] - m - ls;
}

extern "C" void kernel_launch(void* const* d_in, const int* in_sizes, int n_in, void* d_out,
                              int out_size, void* d_ws, size_t ws_size, hipStream_t stream) {
    (void)in_sizes; (void)n_in; (void)out_size; (void)ws_size;
    const float* x = (const float*)d_in[0];
    const float *cw[8], *cb[8], *cg[8], *ct[8];
    for (int i = 0; i < 8; ++i) {
        cw[i] = (const float*)d_in[1 + 4 * i];
        cb[i] = (const float*)d_in[2 + 4 * i];
        cg[i] = (const float*)d_in[3 + 4 * i];
        ct[i] = (const float*)d_in[4 + 4 * i];
    }
    const float *lw[3], *lb[3], *lg[3], *lt[3];
    for (int i = 0; i < 3; ++i) {
        lw[i] = (const float*)d_in[33 + 4 * i];
        lb[i] = (const float*)d_in[34 + 4 * i];
        lg[i] = (const float*)d_in[35 + 4 * i];
        lt[i] = (const float*)d_in[36 + 4 * i];
    }

    static const int CIs[8] = {3, 64, 128, 256, 256, 512, 512, 512};
    static const int COs[8] = {64, 128, 256, 256, 512, 512, 512, 512};
    static const int HPs[8] = {16, 8, 8, 4, 4, 2, 2, 1};  // output spatial (post-pool)

    char* ws = (char*)d_ws;
    size_t off = 0;
    auto alloc = [&](size_t bytes) -> void* {
        void* p = ws + off;
        off += (bytes + 255) & ~(size_t)255;
        return p;
    };

    u64* wpk[8];
    for (int i = 1; i < 8; ++i) wpk[i] = (u64*)alloc((size_t)COs[i] * 9 * (CIs[i] / 64) * 8);
    u64* wpl[3];
    int LO[3] = {512, 512, 10};
    for (int i = 0; i < 3; ++i) wpl[i] = (u64*)alloc((size_t)LO[i] * 8 * 8);
    u64* act[8];
    for (int i = 0; i < 8; ++i) act[i] = (u64*)alloc((size_t)256 * (COs[i] / 64) * HPs[i] * HPs[i] * 8);
    u64* fcs0 = (u64*)alloc(2048 * 8);
    u64* fcs1 = (u64*)alloc(2048 * 8);
    float* preA = (float*)alloc((size_t)4194304 * 4);
    float* preB = (float*)alloc((size_t)2097152 * 4);
    float2* stats = (float2*)alloc(512 * 8);
    float* z0 = (float*)alloc((size_t)256 * 512 * 4);
    float* z1 = (float*)alloc((size_t)256 * 512 * 4);
    float* z2 = (float*)alloc((size_t)256 * 10 * 4);
    // stats accumulators: layer0 doubles + layers1..7 int64, each 512*2 words of 8B
    u64* accs = (u64*)alloc((size_t)8 * 512 * 2 * 8);
    double* dacc0 = (double*)accs;
    auto iacc = [&](int layer) { return accs + (size_t)layer * 1024; };

    // ---- zero accumulators (ws is poisoned every call) ----
    zero_acc<<<(8 * 512 * 2 + 255) / 256, 256, 0, stream>>>(accs, 8 * 512 * 2);

    // ---- pack weights ----
    for (int i = 1; i < 8; ++i) {
        int total = COs[i] * 9 * (CIs[i] / 64);
        wpack_conv<<<(total + 255) / 256, 256, 0, stream>>>(cw[i], wpk[i], COs[i], CIs[i]);
    }
    for (int i = 0; i < 3; ++i) {
        int total = LO[i] * 8;
        wpack_lin<<<(total + 255) / 256, 256, 0, stream>>>(lw[i], wpl[i], LO[i]);
    }

    // ---- conv0 (real input), fused stats ----
    conv0_kernel<<<dim3(256, 64), 256, 0, stream>>>(x, cw[0], cb[0], preA, dacc0);
    finalize_dbl<<<1, 256, 0, stream>>>(dacc0, cb[0], stats, 64, 256 * 256);
    bnpack_kernel<<<(256 * 1 * 256 + 255) / 256, 256, 0, stream>>>(preA, stats, cg[0], ct[0],
                                                                   act[0], 64, 256);
    // ---- conv1: 64ch 16x16 -> 128ch, pool -> 8x8 ----
    bconv_kernel<1, 16, true><<<dim3(64, 128), 256, 0, stream>>>(act[0], wpk[1], cb[1], preB, 128,
                                                                 iacc(1));
    finalize_int<<<1, 256, 0, stream>>>(iacc(1), cb[1], stats, 128, 256 * 64);
    bnpack_kernel<<<(256 * 2 * 64 + 255) / 256, 256, 0, stream>>>(preB, stats, cg[1], ct[1], act[1],
                                                                  128, 64);
    // ---- conv2: 128ch 8x8 -> 256ch (no pool) ----
    bconv_kernel<2, 8, false><<<dim3(64, 256), 256, 0, stream>>>(act[1], wpk[2], cb[2], preA, 256,
                                                                 iacc(2));
    finalize_int<<<1, 256, 0, stream>>>(iacc(2), cb[2], stats, 256, 256 * 64);
    bnpack_kernel<<<(256 * 4 * 64 + 255) / 256, 256, 0, stream>>>(preA, stats, cg[2], ct[2], act[2],
                                                                  256, 64);
    // ---- conv3: 256ch 8x8 -> 256ch, pool -> 4x4 ----
    bconv_kernel<4, 8, true><<<dim3(16, 256), 256, 0, stream>>>(act[2], wpk[3], cb[3], preB, 256,
                                                                iacc(3));
    finalize_int<<<1, 256, 0, stream>>>(iacc(3), cb[3], stats, 256, 256 * 16);
    bnpack_kernel<<<(256 * 4 * 16 + 255) / 256, 256, 0, stream>>>(preB, stats, cg[3], ct[3], act[3],
                                                                  256, 16);
    // ---- conv4: 256ch 4x4 -> 512ch (no pool) ----
    bconv_kernel<4, 4, false><<<dim3(16, 512), 256, 0, stream>>>(act[3], wpk[4], cb[4], preA, 512,
                                                                 iacc(4));
    finalize_int<<<2, 256, 0, stream>>>(iacc(4), cb[4], stats, 512, 256 * 16);
    bnpack_kernel<<<(256 * 8 * 16 + 255) / 256, 256, 0, stream>>>(preA, stats, cg[4], ct[4], act[4],
                                                                  512, 16);
    // ---- conv5: 512ch 4x4 -> 512ch, pool -> 2x2 ----
    bconv_kernel<8, 4, true><<<dim3(4, 512), 256, 0, stream>>>(act[4], wpk[5], cb[5], preB, 512,
                                                               iacc(5));
    finalize_int<<<2, 256, 0, stream>>>(iacc(5), cb[5], stats, 512, 256 * 4);
    bnpack_kernel<<<(256 * 8 * 4 + 255) / 256, 256, 0, stream>>>(preB, stats, cg[5], ct[5], act[5],
                                                                 512, 4);
    // ---- conv6: 512ch 2x2 -> 512ch (no pool) ----
    bconv_kernel<8, 2, false><<<dim3(4, 512), 256, 0, stream>>>(act[5], wpk[6], cb[6], preA, 512,
                                                                iacc(6));
    finalize_int<<<2, 256, 0, stream>>>(iacc(6), cb[6], stats, 512, 256 * 4);
    bnpack_kernel<<<(256 * 8 * 4 + 255) / 256, 256, 0, stream>>>(preA, stats, cg[6], ct[6], act[6],
                                                                 512, 4);
    // ---- conv7: 512ch 2x2 -> 512ch, pool -> 1x1 ----
    bconv_kernel<8, 2, true><<<dim3(1, 512), 256, 0, stream>>>(act[6], wpk[7], cb[7], preB, 512,
                                                               iacc(7));
    finalize_int<<<2, 256, 0, stream>>>(iacc(7), cb[7], stats, 512, 256 * 1);
    bnpack_kernel<<<(256 * 8 * 1 + 255) / 256, 256, 0, stream>>>(preB, stats, cg[7], ct[7], act[7],
                                                                 512, 1);

    // ---- FC ----
    lin_kernel<<<512, 256, 0, stream>>>(act[7], wpl[0], lb[0], lg[0], lt[0], z0, 512, 1);
    pack_rows<<<8, 256, 0, stream>>>(z0, fcs0);
    lin_kernel<<<512, 256, 0, stream>>>(fcs0, wpl[1], lb[1], lg[1], lt[1], z1, 512, 1);
    pack_rows<<<8, 256, 0, stream>>>(z1, fcs1);
    lin_kernel<<<10, 256, 0, stream>>>(fcs1, wpl[2], lb[2], lg[2], lt[2], z2, 10, 0);
    lsm_kernel<<<4, 64, 0, stream>>>(z2, (float*)d_out);
}

// Round 3
// 595.514 us; speedup vs baseline: 1.3287x; 1.2644x over previous
//
#include <hip/hip_runtime.h>
#include <hip/hip_bf16.h>

typedef unsigned long long u64;

#define EPSV 1e-5

__device__ __forceinline__ int imax(int a, int b) { return a > b ? a : b; }
__device__ __forceinline__ int iclamp(int v, int lo, int hi) { return v < lo ? lo : (v > hi ? hi : v); }

// ================= prep: pack all binary weights + zero stats accumulators =================
struct PrepArgs {
    const float* src[10];  // conv1..7, lin0..2
    u64* dst[10];          // [co][9][CW] for conv; [o][8] for lin
    u64* dstT[10];         // transposed [k*CW+w][Co] for tiny layers (conv5,6,7), else null
    int ci[10];            // input channels (0 => linear layer)
    int co[10];
    int base[11];          // prefix word offsets
    u64* accs;
    int naccs;
};

__global__ __launch_bounds__(256) void prep_kernel(PrepArgs a) {
    int idx = blockIdx.x * 256 + threadIdx.x;
    if (idx < a.naccs) a.accs[idx] = 0ULL;
    if (idx >= a.base[10]) return;
    int l = 0;
    while (l < 9 && idx >= a.base[l + 1]) ++l;
    int local = idx - a.base[l];
    u64 bits = 0;
    if (a.ci[l] > 0) {
        int CW = a.ci[l] >> 6;
        int ww = local % CW;
        int t = local / CW;
        int k = t % 9;
        int c_o = t / 9;
        int ky = k / 3, kx = k % 3;
        const float* s = a.src[l];
        for (int j = 0; j < 64; ++j)
            bits |= (u64)(s[(((size_t)c_o * a.ci[l] + ww * 64 + j) * 3 + ky) * 3 + kx] >= 0.f) << j;
        a.dst[l][local] = bits;
        if (a.dstT[l]) a.dstT[l][(size_t)(k * CW + ww) * a.co[l] + c_o] = bits;
    } else {
        int ww = local & 7;
        int o = local >> 3;
        const float* row = a.src[l] + (size_t)o * 512 + ww * 64;
        for (int j = 0; j < 64; ++j) bits |= (u64)(row[j] >= 0.f) << j;
        a.dst[l][local] = bits;
    }
}

// ================= conv0: real input, binarized weights, 3x3 pad1 + maxpool2 =================
// grid (256, 2): x = pixel blocks (thread per post-pool pixel), y = 32-co chunk
// out: float [n][256 px][64 co] (pre-BN, NO bias — bias cancels in BN)
__global__ __launch_bounds__(256) void conv0_kernel(const float* __restrict__ x,
                                                    const float* __restrict__ wgt,
                                                    float* __restrict__ out) {
    __shared__ float ws[32 * 27];
    const int co0 = blockIdx.y * 32;
    for (int t = threadIdx.x; t < 32 * 27; t += 256) {
        int c = t / 27, k = t % 27;
        ws[t] = (wgt[(co0 + c) * 27 + k] >= 0.f) ? 1.f : -1.f;
    }
    __syncthreads();
    int idx = blockIdx.x * 256 + threadIdx.x;  // n*256 + yp*16 + xp
    const int xp = idx & 15;
    const int yp = (idx >> 4) & 15;
    const int n = idx >> 8;
    const float* xb = x + (size_t)n * 3072;
    const int y0 = 2 * yp - 1, x0 = 2 * xp - 1;

    float win[3][4][4];
#pragma unroll
    for (int ci = 0; ci < 3; ++ci)
#pragma unroll
        for (int r = 0; r < 4; ++r) {
            int yy = y0 + r;
            int yyc = iclamp(yy, 0, 31);
#pragma unroll
            for (int c = 0; c < 4; ++c) {
                int xx = x0 + c;
                int xxc = iclamp(xx, 0, 31);
                float v = xb[(ci * 32 + yyc) * 32 + xxc];
                win[ci][r][c] = (yy == yyc && xx == xxc) ? v : 0.f;
            }
        }

    float* op = out + (size_t)idx * 64 + co0;
#pragma unroll 1
    for (int cc = 0; cc < 32; cc += 4) {
        float4 o4;
        float vals[4];
#pragma unroll
        for (int u = 0; u < 4; ++u) {
            const float* wc = &ws[(cc + u) * 27];
            float a00 = 0.f, a01 = 0.f, a10 = 0.f, a11 = 0.f;
#pragma unroll
            for (int ci = 0; ci < 3; ++ci)
#pragma unroll
                for (int ky = 0; ky < 3; ++ky)
#pragma unroll
                    for (int kx = 0; kx < 3; ++kx) {
                        float wv = wc[ci * 9 + ky * 3 + kx];
                        a00 += win[ci][ky][kx] * wv;
                        a01 += win[ci][ky][kx + 1] * wv;
                        a10 += win[ci][ky + 1][kx] * wv;
                        a11 += win[ci][ky + 1][kx + 1] * wv;
                    }
            vals[u] = fmaxf(fmaxf(a00, a01), fmaxf(a10, a11));
        }
        o4.x = vals[0]; o4.y = vals[1]; o4.z = vals[2]; o4.w = vals[3];
        *(float4*)(op + cc) = o4;
    }
}

// ================= stats0: double sums of conv0 output per channel =================
__global__ __launch_bounds__(256) void stats0_kernel(const float* __restrict__ out0,
                                                     double* __restrict__ dacc) {
    const int co = threadIdx.x & 63;
    const int pr = threadIdx.x >> 6;
    const int base = blockIdx.x * 256;  // 256 pixels per block, 65536 total
    double s1 = 0.0, s2 = 0.0;
    for (int i = 0; i < 64; ++i) {
        float v = out0[(size_t)(base + pr * 64 + i) * 64 + co];
        s1 += (double)v;
        s2 += (double)v * (double)v;
    }
    __shared__ double sh[2][4][64];
    sh[0][pr][co] = s1;
    sh[1][pr][co] = s2;
    __syncthreads();
    if (threadIdx.x < 64) {
        double t1 = 0.0, t2 = 0.0;
        for (int r = 0; r < 4; ++r) { t1 += sh[0][r][threadIdx.x]; t2 += sh[1][r][threadIdx.x]; }
        atomicAdd(&dacc[2 * threadIdx.x], t1);
        atomicAdd(&dacc[2 * threadIdx.x + 1], t2);
    }
}

// ================= finalize (float variant, layer 0) =================
// thr = {threshold, sgn}: bit = sgn>0 ? v>=thr : v<=thr
__global__ void finalize_f(const double* __restrict__ dacc, const float* __restrict__ g,
                           const float* __restrict__ b, float2* __restrict__ thr, int Co,
                           int count) {
    int i = blockIdx.x * blockDim.x + threadIdx.x;
    if (i >= Co) return;
    double m = dacc[2 * i] / count;
    double var = dacc[2 * i + 1] / count - m * m;
    double istd = 1.0 / sqrt(var + EPSV);
    double s = (double)g[i] * istd;
    float2 r;
    if (s == 0.0) {
        r = make_float2(b[i] >= 0.f ? -3.0e38f : 3.0e38f, 1.f);
    } else {
        double t = m - (double)b[i] / s;
        r = make_float2((float)t, s > 0.0 ? 1.f : -1.f);
    }
    thr[i] = r;
}

// ================= bnpack for float input (layer 0) =================
// in: float [n][256][64]; out: act words [n][p] (CW=1)
__global__ __launch_bounds__(256) void bnpack_f(const float* __restrict__ in,
                                                const float2* __restrict__ thr,
                                                u64* __restrict__ act) {
    int idx = blockIdx.x * 256 + threadIdx.x;  // 65536
    const float4* r4 = (const float4*)(in + (size_t)idx * 64);
    u64 bits = 0;
#pragma unroll
    for (int b = 0; b < 16; ++b) {
        float4 q = r4[b];
        float vv[4] = {q.x, q.y, q.z, q.w};
#pragma unroll
        for (int u = 0; u < 4; ++u) {
            int c = b * 4 + u;
            float2 t = thr[c];
            bool bit = (t.y > 0.f) ? (vv[u] >= t.x) : (vv[u] <= t.x);
            bits |= (u64)bit << c;
        }
    }
    act[idx] = bits;
}

// ================= finalize (int variant, layers 1..7) =================
// thr = {ti, mode}: bit = mode ? (v<=ti) : (v>=ti)
__global__ void finalize_i(const u64* __restrict__ iacc, const float* __restrict__ g,
                           const float* __restrict__ b, int2* __restrict__ thr, int Co,
                           int count) {
    int i = blockIdx.x * blockDim.x + threadIdx.x;
    if (i >= Co) return;
    long long S1 = (long long)iacc[2 * i];
    long long S2 = (long long)iacc[2 * i + 1];
    double m = (double)S1 / count;
    double var = (double)S2 / count - m * m;
    double istd = 1.0 / sqrt(var + EPSV);
    double s = (double)g[i] * istd;
    int2 r;
    if (s == 0.0) {
        r = make_int2(b[i] >= 0.f ? (int)0x80000000 : 0x7fffffff, 0);
    } else {
        double t = m - (double)b[i] / s;
        if (t > 1.0e9) t = 1.0e9;
        if (t < -1.0e9) t = -1.0e9;
        if (s > 0.0) r = make_int2((int)ceil(t), 0);
        else r = make_int2((int)floor(t), 1);
    }
    thr[i] = r;
}

// ================= bnpack for int16 input (layers 1..7) =================
// in: int16 [n][HW px][Co]; act: word at [n][w][p]
__global__ __launch_bounds__(256) void bnpack_i(const short* __restrict__ in,
                                                const int2* __restrict__ thr,
                                                u64* __restrict__ act, int Co, int CW, int HW) {
    int idx = blockIdx.x * 256 + threadIdx.x;  // n*(CW*HW) + w*HW + p
    int p = idx % HW;
    int w = (idx / HW) % CW;
    int n = idx / (HW * CW);
    const int4* r4 = (const int4*)(in + ((size_t)(n * HW + p)) * Co + w * 64);
    u64 bits = 0;
#pragma unroll
    for (int b = 0; b < 8; ++b) {
        int4 q = r4[b];
        int words[4] = {q.x, q.y, q.z, q.w};
#pragma unroll
        for (int u = 0; u < 4; ++u) {
#pragma unroll
            for (int h = 0; h < 2; ++h) {
                int c = b * 8 + u * 2 + h;
                int v = (int)(short)((h == 0) ? (words[u] & 0xffff) : ((unsigned)words[u] >> 16));
                int2 t = thr[w * 64 + c];
                bool bit = t.y ? (v <= t.x) : (v >= t.x);
                bits |= (u64)bit << c;
            }
        }
    }
    act[idx] = bits;
}

// ================= binary conv, co-chunked (layers 1..4) =================
// in: words [n][CW][HIN][HIN]; wpk: [co][9][CW]; out: int16 [n][HP*HP][Co]; iacc: {S1,S2} per ch
template <int CW, int HIN, bool POOL, int COB>
__global__ __launch_bounds__(256) void bconv_kernel(const u64* __restrict__ in,
                                                    const u64* __restrict__ wpk,
                                                    short* __restrict__ out,
                                                    u64* __restrict__ iacc, int Co) {
    constexpr int HP = POOL ? HIN / 2 : HIN;
    constexpr int WS = POOL ? 4 : 3;
    constexpr int NPP = POOL ? 4 : 1;
    __shared__ u64 wl[COB * CW * 9];
    const int co0 = blockIdx.y * COB;
    for (int t = threadIdx.x; t < COB * CW * 9; t += 256) {
        int c = t / (CW * 9);
        int rem = t % (CW * 9);
        int w = rem / 9, k = rem % 9;
        wl[(c * CW + w) * 9 + k] = wpk[(size_t)(co0 + c) * 9 * CW + k * CW + w];
    }
    __syncthreads();

    int idx = blockIdx.x * 256 + threadIdx.x;  // exact: 256*HP*HP threads
    const int xp = idx % HP;
    int t2 = idx / HP;
    const int yp = t2 % HP;
    const int n = t2 / HP;
    const int y0 = (POOL ? 2 * yp : yp) - 1;
    const int x0 = (POOL ? 2 * xp : xp) - 1;

    int offc[WS][WS];
    bool vld[WS][WS];
#pragma unroll
    for (int r = 0; r < WS; ++r) {
        int yy = y0 + r;
        int yyc = iclamp(yy, 0, HIN - 1);
#pragma unroll
        for (int c = 0; c < WS; ++c) {
            int xx = x0 + c;
            int xxc = iclamp(xx, 0, HIN - 1);
            offc[r][c] = yyc * HIN + xxc;
            vld[r][c] = (yy == yyc) && (xx == xxc);
        }
    }

    const u64* inb = in + (size_t)n * CW * HIN * HIN;
    int acc[COB * NPP];
#pragma unroll
    for (int i = 0; i < COB * NPP; ++i) acc[i] = 0;

#pragma unroll 1
    for (int w = 0; w < CW; ++w) {
        u64 win[WS][WS];
#pragma unroll
        for (int r = 0; r < WS; ++r)
#pragma unroll
            for (int c = 0; c < WS; ++c) win[r][c] = inb[w * HIN * HIN + offc[r][c]];
#pragma unroll
        for (int c = 0; c < COB; ++c) {
            const u64* wr = &wl[(c * CW + w) * 9];
            u64 wb[9];
#pragma unroll
            for (int k = 0; k < 9; ++k) wb[k] = wr[k];
            if constexpr (POOL) {
#pragma unroll
                for (int py = 0; py < 2; ++py)
#pragma unroll
                    for (int px = 0; px < 2; ++px)
#pragma unroll
                        for (int ky = 0; ky < 3; ++ky)
#pragma unroll
                            for (int kx = 0; kx < 3; ++kx) {
                                int pcv = 64 - 2 * (int)__popcll(win[py + ky][px + kx] ^ wb[ky * 3 + kx]);
                                acc[c * 4 + py * 2 + px] += vld[py + ky][px + kx] ? pcv : 0;
                            }
            } else {
#pragma unroll
                for (int ky = 0; ky < 3; ++ky)
#pragma unroll
                    for (int kx = 0; kx < 3; ++kx) {
                        int pcv = 64 - 2 * (int)__popcll(win[ky][kx] ^ wb[ky * 3 + kx]);
                        acc[c] += vld[ky][kx] ? pcv : 0;
                    }
            }
        }
    }

    // epilogue: pool, store, stats
    int ivals[COB];
#pragma unroll
    for (int c = 0; c < COB; ++c) {
        if constexpr (POOL)
            ivals[c] = imax(imax(acc[c * 4], acc[c * 4 + 1]), imax(acc[c * 4 + 2], acc[c * 4 + 3]));
        else
            ivals[c] = acc[c];
    }
    union { short s[COB]; int4 v[COB / 8]; } uv;
#pragma unroll
    for (int c = 0; c < COB; ++c) uv.s[c] = (short)ivals[c];
    int4* dst = (int4*)(out + (size_t)idx * Co + co0);
#pragma unroll
    for (int q = 0; q < COB / 8; ++q) dst[q] = uv.v[q];

    const int lane = threadIdx.x & 63;
#pragma unroll
    for (int c = 0; c < COB; ++c) {
        int s1 = ivals[c];
        int s2 = ivals[c] * ivals[c];
#pragma unroll
        for (int off = 32; off > 0; off >>= 1) {
            s1 += __shfl_down(s1, off);
            s2 += __shfl_down(s2, off);
        }
        if (lane == 0) {
            atomicAdd(&iacc[2 * (co0 + c)], (u64)(long long)s1);
            atomicAdd(&iacc[2 * (co0 + c) + 1], (u64)(long long)s2);
        }
    }
}

// ================= binary conv for tiny images (layers 5..7, HIN in {2,4}) =================
// thread = (n, co); lane = co_local -> weight reads coalesced via wpkT [k*CW+w][Co];
// image words wave-uniform (broadcast). Tap validity compile-time. grid (64, Co/64)
template <int CW, int HIN, bool POOL>
__global__ __launch_bounds__(256) void bconv_tiny(const u64* __restrict__ in,
                                                  const u64* __restrict__ wpkT,
                                                  short* __restrict__ out,
                                                  u64* __restrict__ iacc, int Co) {
    constexpr int NPX = HIN * HIN;
    constexpr int HP = POOL ? HIN / 2 : HIN;
    const int lane = threadIdx.x & 63;
    const int co = blockIdx.y * 64 + lane;
    const int n = blockIdx.x * 4 + (threadIdx.x >> 6);
    const u64* inb = in + (size_t)n * CW * NPX;
    int acc[NPX];
#pragma unroll
    for (int i = 0; i < NPX; ++i) acc[i] = 0;

#pragma unroll 1
    for (int w = 0; w < CW; ++w) {
        u64 win[NPX];
#pragma unroll
        for (int i = 0; i < NPX; ++i) win[i] = inb[w * NPX + i];
#pragma unroll
        for (int k = 0; k < 9; ++k) {
            u64 wb = wpkT[(size_t)(k * CW + w) * Co + co];
            const int ky = k / 3, kx = k % 3;
#pragma unroll
            for (int py = 0; py < HIN; ++py)
#pragma unroll
                for (int px = 0; px < HIN; ++px) {
                    const int yy = py + ky - 1, xx = px + kx - 1;
                    if (yy >= 0 && yy < HIN && xx >= 0 && xx < HIN)  // compile-time foldable
                        acc[py * HIN + px] += 64 - 2 * (int)__popcll(win[yy * HIN + xx] ^ wb);
                }
        }
    }

    short vals[HP * HP];
    if constexpr (POOL) {
#pragma unroll
        for (int py = 0; py < HP; ++py)
#pragma unroll
            for (int px = 0; px < HP; ++px)
                vals[py * HP + px] = (short)imax(
                    imax(acc[(2 * py) * HIN + 2 * px], acc[(2 * py) * HIN + 2 * px + 1]),
                    imax(acc[(2 * py + 1) * HIN + 2 * px], acc[(2 * py + 1) * HIN + 2 * px + 1]));
    } else {
#pragma unroll
        for (int i = 0; i < NPX; ++i) vals[i] = (short)acc[i];
    }
#pragma unroll
    for (int p = 0; p < HP * HP; ++p) out[(size_t)(n * HP * HP + p) * Co + co] = vals[p];

    long long s1 = 0, s2 = 0;
#pragma unroll
    for (int p = 0; p < HP * HP; ++p) {
        s1 += vals[p];
        s2 += (long long)vals[p] * vals[p];
    }
    __shared__ u64 sacc[128];
    if (threadIdx.x < 128) sacc[threadIdx.x] = 0ULL;
    __syncthreads();
    atomicAdd(&sacc[lane], (u64)s1);
    atomicAdd(&sacc[64 + lane], (u64)s2);
    __syncthreads();
    if (threadIdx.x < 64)
        atomicAdd(&iacc[2 * (blockIdx.y * 64 + threadIdx.x)], sacc[threadIdx.x]);
    else if (threadIdx.x < 128)
        atomicAdd(&iacc[2 * (blockIdx.y * 64 + threadIdx.x - 64) + 1], sacc[threadIdx.x]);
}

// ================= binarized linear + BN1 (+ hardtanh) =================
__global__ __launch_bounds__(256) void lin_kernel(const u64* __restrict__ hp,
                                                  const u64* __restrict__ wp,
                                                  const float* __restrict__ lb,
                                                  const float* __restrict__ g,
                                                  const float* __restrict__ bta,
                                                  float* __restrict__ z, int O, int applyHt) {
    int o = blockIdx.x;
    int n = threadIdx.x;
    const u64* hr = hp + n * 8;
    const u64* wr = wp + o * 8;
    int s = 0;
#pragma unroll
    for (int w = 0; w < 8; ++w) s += (int)__popcll(hr[w] ^ wr[w]);
    float val = (float)(512 - 2 * s) + lb[o];
    __shared__ double sh1[256], sh2[256];
    sh1[n] = (double)val;
    sh2[n] = (double)val * (double)val;
    __syncthreads();
    for (int st = 128; st > 0; st >>= 1) {
        if (n < st) {
            sh1[n] += sh1[n + st];
            sh2[n] += sh2[n + st];
        }
        __syncthreads();
    }
    __shared__ float sm, siv;
    if (n == 0) {
        double m = sh1[0] / 256.0;
        double var = sh2[0] / 256.0 - m * m;
        sm = (float)m;
        siv = (float)(1.0 / sqrt(var + EPSV));
    }
    __syncthreads();
    float zz = g[o] * (val - sm) * siv + bta[o];
    if (applyHt) zz = fminf(1.f, fmaxf(-1.f, zz));
    z[(size_t)n * O + o] = zz;
}

__global__ void pack_rows(const float* __restrict__ z, u64* __restrict__ hp) {
    int idx = blockIdx.x * 256 + threadIdx.x;
    if (idx >= 2048) return;
    int ww = idx & 7;
    int n = idx >> 3;
    u64 bits = 0;
    const float* row = z + (size_t)n * 512 + (ww << 6);
    for (int j = 0; j < 64; ++j) bits |= (u64)(row[j] >= 0.f) << j;
    hp[idx] = bits;
}

__global__ void lsm_kernel(const float* __restrict__ z, float* __restrict__ out) {
    int n = blockIdx.x * 64 + threadIdx.x;
    if (n >= 256) return;
    float v[10];
    float m = -1e30f;
#pragma unroll
    for (int i = 0; i < 10; ++i) {
        v[i] = z[n * 10 + i];
        m = fmaxf(m, v[i]);
    }
    float s = 0.f;
#pragma unroll
    for (int i = 0; i < 10; ++i) s += expf(v[i] - m);
    float ls = logf(s);
#pragma unroll
    for (int i = 0; i < 10; ++i) out[n * 10 + i] = v[i] - m - ls;
}

extern "C" void kernel_launch(void* const* d_in, const int* in_sizes, int n_in, void* d_out,
                              int out_size, void* d_ws, size_t ws_size, hipStream_t stream) {
    (void)in_sizes; (void)n_in; (void)out_size; (void)ws_size;
    const float* x = (const float*)d_in[0];
    const float *cw[8], *cb[8], *cg[8], *ct[8];
    for (int i = 0; i < 8; ++i) {
        cw[i] = (const float*)d_in[1 + 4 * i];
        cb[i] = (const float*)d_in[2 + 4 * i];
        cg[i] = (const float*)d_in[3 + 4 * i];
        ct[i] = (const float*)d_in[4 + 4 * i];
    }
    const float *lw[3], *lb[3], *lg[3], *lt[3];
    for (int i = 0; i < 3; ++i) {
        lw[i] = (const float*)d_in[33 + 4 * i];
        lb[i] = (const float*)d_in[34 + 4 * i];
        lg[i] = (const float*)d_in[35 + 4 * i];
        lt[i] = (const float*)d_in[36 + 4 * i];
    }

    static const int CIs[8] = {3, 64, 128, 256, 256, 512, 512, 512};
    static const int COs[8] = {64, 128, 256, 256, 512, 512, 512, 512};
    static const int HPs[8] = {16, 8, 8, 4, 4, 2, 2, 1};

    char* ws = (char*)d_ws;
    size_t off = 0;
    auto alloc = [&](size_t bytes) -> void* {
        void* p = ws + off;
        off += (bytes + 255) & ~(size_t)255;
        return p;
    };

    u64* wpk[8];
    for (int i = 1; i < 8; ++i) wpk[i] = (u64*)alloc((size_t)COs[i] * 9 * (CIs[i] / 64) * 8);
    u64* wpkT[8] = {};
    for (int i = 5; i < 8; ++i) wpkT[i] = (u64*)alloc((size_t)COs[i] * 9 * (CIs[i] / 64) * 8);
    u64* wpl[3];
    int LO[3] = {512, 512, 10};
    for (int i = 0; i < 3; ++i) wpl[i] = (u64*)alloc((size_t)LO[i] * 8 * 8);
    u64* act[8];
    for (int i = 0; i < 8; ++i) act[i] = (u64*)alloc((size_t)256 * (COs[i] / 64) * HPs[i] * HPs[i] * 8);
    u64* fcs0 = (u64*)alloc(2048 * 8);
    u64* fcs1 = (u64*)alloc(2048 * 8);
    float* out0 = (float*)alloc((size_t)65536 * 64 * 4);   // conv0 pre-BN [px][64]
    short* i16A = (short*)alloc((size_t)16384 * 256 * 2);  // ping
    short* i16B = (short*)alloc((size_t)16384 * 256 * 2);  // pong
    float2* thrF = (float2*)alloc(64 * 8);
    int2* thrI = (int2*)alloc(512 * 8);
    float* z0 = (float*)alloc((size_t)256 * 512 * 4);
    float* z1 = (float*)alloc((size_t)256 * 512 * 4);
    float* z2 = (float*)alloc((size_t)256 * 10 * 4);
    u64* accs = (u64*)alloc((size_t)8 * 512 * 2 * 8);
    double* dacc0 = (double*)accs;
    auto iacc = [&](int layer) { return accs + (size_t)layer * 1024; };

    // ---- prep: pack all weights + zero accumulators ----
    PrepArgs pa;
    int wbase = 0;
    for (int i = 1; i < 8; ++i) {
        int e = i - 1;
        pa.src[e] = cw[i];
        pa.dst[e] = wpk[i];
        pa.dstT[e] = (i >= 5) ? wpkT[i] : nullptr;
        pa.ci[e] = CIs[i];
        pa.co[e] = COs[i];
        pa.base[e] = wbase;
        wbase += COs[i] * 9 * (CIs[i] / 64);
    }
    for (int i = 0; i < 3; ++i) {
        int e = 7 + i;
        pa.src[e] = lw[i];
        pa.dst[e] = wpl[i];
        pa.dstT[e] = nullptr;
        pa.ci[e] = 0;
        pa.co[e] = LO[i];
        pa.base[e] = wbase;
        wbase += LO[i] * 8;
    }
    pa.base[10] = wbase;
    pa.accs = accs;
    pa.naccs = 8 * 512 * 2;
    int prep_total = wbase > pa.naccs ? wbase : pa.naccs;
    prep_kernel<<<(prep_total + 255) / 256, 256, 0, stream>>>(pa);

    // ---- L0: conv0 + stats + finalize + pack ----
    conv0_kernel<<<dim3(256, 2), 256, 0, stream>>>(x, cw[0], out0);
    stats0_kernel<<<256, 256, 0, stream>>>(out0, dacc0);
    finalize_f<<<1, 64, 0, stream>>>(dacc0, cg[0], ct[0], thrF, 64, 65536);
    bnpack_f<<<256, 256, 0, stream>>>(out0, thrF, act[0]);

    // ---- L1: 64ch 16x16 -> 128ch, pool -> 8x8 ----
    bconv_kernel<1, 16, true, 8><<<dim3(64, 16), 256, 0, stream>>>(act[0], wpk[1], i16A, iacc(1), 128);
    finalize_i<<<1, 128, 0, stream>>>(iacc(1), cg[1], ct[1], thrI, 128, 16384);
    bnpack_i<<<128, 256, 0, stream>>>(i16A, thrI, act[1], 128, 2, 64);

    // ---- L2: 128ch 8x8 -> 256ch ----
    bconv_kernel<2, 8, false, 16><<<dim3(64, 16), 256, 0, stream>>>(act[1], wpk[2], i16B, iacc(2), 256);
    finalize_i<<<1, 256, 0, stream>>>(iacc(2), cg[2], ct[2], thrI, 256, 16384);
    bnpack_i<<<256, 256, 0, stream>>>(i16B, thrI, act[2], 256, 4, 64);

    // ---- L3: 256ch 8x8 -> 256ch, pool -> 4x4 ----
    bconv_kernel<4, 8, true, 8><<<dim3(16, 32), 256, 0, stream>>>(act[2], wpk[3], i16A, iacc(3), 256);
    finalize_i<<<1, 256, 0, stream>>>(iacc(3), cg[3], ct[3], thrI, 256, 4096);
    bnpack_i<<<64, 256, 0, stream>>>(i16A, thrI, act[3], 256, 4, 16);

    // ---- L4: 256ch 4x4 -> 512ch ----
    bconv_kernel<4, 4, false, 16><<<dim3(16, 32), 256, 0, stream>>>(act[3], wpk[4], i16B, iacc(4), 512);
    finalize_i<<<2, 256, 0, stream>>>(iacc(4), cg[4], ct[4], thrI, 512, 4096);
    bnpack_i<<<128, 256, 0, stream>>>(i16B, thrI, act[4], 512, 8, 16);

    // ---- L5: 512ch 4x4 -> 512ch, pool -> 2x2 (tiny) ----
    bconv_tiny<8, 4, true><<<dim3(64, 8), 256, 0, stream>>>(act[4], wpkT[5], i16A, iacc(5), 512);
    finalize_i<<<2, 256, 0, stream>>>(iacc(5), cg[5], ct[5], thrI, 512, 1024);
    bnpack_i<<<32, 256, 0, stream>>>(i16A, thrI, act[5], 512, 8, 4);

    // ---- L6: 512ch 2x2 -> 512ch (tiny) ----
    bconv_tiny<8, 2, false><<<dim3(64, 8), 256, 0, stream>>>(act[5], wpkT[6], i16B, iacc(6), 512);
    finalize_i<<<2, 256, 0, stream>>>(iacc(6), cg[6], ct[6], thrI, 512, 1024);
    bnpack_i<<<32, 256, 0, stream>>>(i16B, thrI, act[6], 512, 8, 4);

    // ---- L7: 512ch 2x2 -> 512ch, pool -> 1x1 (tiny) ----
    bconv_tiny<8, 2, true><<<dim3(64, 8), 256, 0, stream>>>(act[6], wpkT[7], i16A, iacc(7), 512);
    finalize_i<<<2, 256, 0, stream>>>(iacc(7), cg[7], ct[7], thrI, 512, 256);
    bnpack_i<<<8, 256, 0, stream>>>(i16A, thrI, act[7], 512, 8, 1);

    // ---- FC ----
    lin_kernel<<<512, 256, 0, stream>>>(act[7], wpl[0], lb[0], lg[0], lt[0], z0, 512, 1);
    pack_rows<<<8, 256, 0, stream>>>(z0, fcs0);
    lin_kernel<<<512, 256, 0, stream>>>(fcs0, wpl[1], lb[1], lg[1], lt[1], z1, 512, 1);
    pack_rows<<<8, 256, 0, stream>>>(z1, fcs1);
    lin_kernel<<<10, 256, 0, stream>>>(fcs1, wpl[2], lb[2], lg[2], lt[2], z2, 10, 0);
    lsm_kernel<<<4, 64, 0, stream>>>(z2, (float*)d_out);
}